// Round 2
// baseline (21177.417 us; speedup 1.0000x reference)
//
#include <hip/hip_runtime.h>
#include <hip/hip_bf16.h>
#include <cstdint>

#define NN 40000
#define NE 100000
#define NB 1024

typedef unsigned short ushortT;
typedef unsigned int uintT;

static __device__ __forceinline__ float sigf(float x){ return 1.f/(1.f + expf(-x)); }
static __device__ __forceinline__ ushortT f2bf(float f){
    uintT u = __float_as_uint(f);
    uintT r = (u + 0x7FFFu + ((u >> 16) & 1u)) >> 16;
    return (ushortT)r;
}
static __device__ __forceinline__ float bf_lo(uintT u){ return __uint_as_float(u << 16); }
static __device__ __forceinline__ float bf_hi(uintT u){ return __uint_as_float(u & 0xFFFF0000u); }

// ---------------- node embed: h = relu(x @ lin0_W^T + b) ----------------
__global__ __launch_bounds__(256) void k_lin0(const float* __restrict__ x,
    const float* __restrict__ W, const float* __restrict__ b, float* __restrict__ h){
    int gid = blockIdx.x * 256 + threadIdx.x;           // NN*32 threads
    int i = gid >> 5, c = gid & 31;
    const float* xr = x + (size_t)i * 30;
    const float* wr = W + (size_t)c * 30;
    float s = b[c];
    #pragma unroll
    for (int f = 0; f < 30; f++) s += xr[f] * wr[f];
    h[gid] = fmaxf(s, 0.f);
}

// ---------------- edge MLP layer 1: eh = relu(edge_attr @ W1^T + b1) ----
__global__ __launch_bounds__(256) void k_edge_mlp(const float* __restrict__ ea,
    const float* __restrict__ W1, const float* __restrict__ b1, float* __restrict__ eh){
    int gid = blockIdx.x * 256 + threadIdx.x;           // NE*128 threads
    int e = gid >> 7, hh = gid & 127;
    const float* xr = ea + (size_t)e * 11;
    const float* wr = W1 + (size_t)hh * 11;
    float s = b1[hh];
    #pragma unroll
    for (int f = 0; f < 11; f++) s += xr[f] * wr[f];
    eh[gid] = fmaxf(s, 0.f);
}

// ---------------- W_e GEMM: WeT[e][p] (p = o*32+c) = eh[e]·W2[j(p)] + b2[j(p)]
// j(p) = (p&31)<<5 | p>>5.  Tile 64 edges x 32 p, fp32, bf16 output.
__global__ __launch_bounds__(256) void k_we_gemm(const float* __restrict__ eh,
    const float* __restrict__ W2, const float* __restrict__ b2,
    ushortT* __restrict__ WeT, int E){
    __shared__ float lds_a[64][129];
    __shared__ float lds_b[32][129];
    int e0 = blockIdx.x * 64;
    int p0 = blockIdx.y * 32;
    int tid = threadIdx.x;
    int k = tid & 127, sub = tid >> 7;
    for (int r = sub; r < 64; r += 2){
        int e = e0 + r;
        lds_a[r][k] = (e < E) ? eh[(size_t)e * 128 + k] : 0.f;
    }
    for (int r = sub; r < 32; r += 2){
        int p = p0 + r;
        int j = ((p & 31) << 5) | (p >> 5);
        lds_b[r][k] = W2[(size_t)j * 128 + k];
    }
    __syncthreads();
    int tp = tid & 7, te = tid >> 3;                    // te: 0..31 (2 edges), tp: 0..7 (4 p)
    float acc[2][4];
    #pragma unroll
    for (int i = 0; i < 2; i++)
        #pragma unroll
        for (int j = 0; j < 4; j++) acc[i][j] = 0.f;
    #pragma unroll 4
    for (int kk = 0; kk < 128; kk++){
        float a0 = lds_a[te * 2 + 0][kk];
        float a1 = lds_a[te * 2 + 1][kk];
        float b0 = lds_b[tp * 4 + 0][kk];
        float b1 = lds_b[tp * 4 + 1][kk];
        float b2v = lds_b[tp * 4 + 2][kk];
        float b3 = lds_b[tp * 4 + 3][kk];
        acc[0][0] += a0 * b0; acc[0][1] += a0 * b1; acc[0][2] += a0 * b2v; acc[0][3] += a0 * b3;
        acc[1][0] += a1 * b0; acc[1][1] += a1 * b1; acc[1][2] += a1 * b2v; acc[1][3] += a1 * b3;
    }
    #pragma unroll
    for (int i = 0; i < 2; i++){
        int e = e0 + te * 2 + i;
        if (e >= E) continue;
        ushort4 sv;
        {
            int p = p0 + tp * 4;
            int j0 = ((p & 31) << 5) | (p >> 5);
            int j1 = (((p + 1) & 31) << 5) | ((p + 1) >> 5);
            int j2 = (((p + 2) & 31) << 5) | ((p + 2) >> 5);
            int j3 = (((p + 3) & 31) << 5) | ((p + 3) >> 5);
            sv.x = f2bf(acc[i][0] + b2[j0]);
            sv.y = f2bf(acc[i][1] + b2[j1]);
            sv.z = f2bf(acc[i][2] + b2[j2]);
            sv.w = f2bf(acc[i][3] + b2[j3]);
        }
        *(ushort4*)&WeT[(size_t)e * 1024 + p0 + tp * 4] = sv;
    }
}

// ---------------- degree & graph counts ----------------
__global__ __launch_bounds__(256) void k_deg(const int* __restrict__ dst, float* __restrict__ deg, int E){
    int e = blockIdx.x * 256 + threadIdx.x;
    if (e < E) atomicAdd(&deg[dst[e]], 1.f);
}
__global__ __launch_bounds__(256) void k_counts(const int* __restrict__ batch, int* __restrict__ counts, int N){
    int i = blockIdx.x * 256 + threadIdx.x;
    if (i < N) atomicAdd(&counts[batch[i]], 1);
}
__global__ __launch_bounds__(1024) void k_scan(const int* __restrict__ counts, int* __restrict__ starts){
    __shared__ int s[1024];
    int t = threadIdx.x;
    s[t] = counts[t];
    __syncthreads();
    for (int off = 1; off < 1024; off <<= 1){
        int v = (t >= off) ? s[t - off] : 0;
        __syncthreads();
        s[t] += v;
        __syncthreads();
    }
    starts[t] = s[t] - counts[t];
    if (t == 1023) starts[1024] = s[1023];
}

// ---------------- message passing: one wave per edge ----------------
__global__ __launch_bounds__(256) void k_msg(const ushortT* __restrict__ WeT,
    const float* __restrict__ h, const int* __restrict__ src, const int* __restrict__ dst,
    float* __restrict__ aggr, int E){
    int wv = (blockIdx.x * 256 + threadIdx.x) >> 6;
    if (wv >= E) return;
    int l = threadIdx.x & 63;
    int e = wv;
    int s = src[e], d = dst[e];
    int o = l >> 1, half = l & 1;
    const ushortT* wp = WeT + (size_t)e * 1024 + o * 32 + half * 16;
    uint4 w0 = *(const uint4*)(wp);
    uint4 w1 = *(const uint4*)(wp + 8);
    const float* up = h + (size_t)s * 32 + half * 16;
    float4 u0 = *(const float4*)(up);
    float4 u1 = *(const float4*)(up + 4);
    float4 u2 = *(const float4*)(up + 8);
    float4 u3 = *(const float4*)(up + 12);
    float p = 0.f;
    p += u0.x * bf_lo(w0.x) + u0.y * bf_hi(w0.x);
    p += u0.z * bf_lo(w0.y) + u0.w * bf_hi(w0.y);
    p += u1.x * bf_lo(w0.z) + u1.y * bf_hi(w0.z);
    p += u1.z * bf_lo(w0.w) + u1.w * bf_hi(w0.w);
    p += u2.x * bf_lo(w1.x) + u2.y * bf_hi(w1.x);
    p += u2.z * bf_lo(w1.y) + u2.w * bf_hi(w1.y);
    p += u3.x * bf_lo(w1.z) + u3.y * bf_hi(w1.z);
    p += u3.z * bf_lo(w1.w) + u3.w * bf_hi(w1.w);
    p += __shfl_xor(p, 1);
    if (half == 0) atomicAdd(&aggr[(size_t)d * 32 + o], p);
}

// fallback (small workspace): recompute W_e row on the fly
__global__ __launch_bounds__(256) void k_msg_slow(const float* __restrict__ eh,
    const float* __restrict__ W2, const float* __restrict__ b2,
    const float* __restrict__ h, const int* __restrict__ src, const int* __restrict__ dst,
    float* __restrict__ aggr, int E){
    int wv = (blockIdx.x * 256 + threadIdx.x) >> 6;
    if (wv >= E) return;
    int l = threadIdx.x & 63;
    int e = wv;
    int s = src[e], d = dst[e];
    int o = l >> 1, half = l & 1;
    const float* up = h + (size_t)s * 32 + half * 16;
    float u[16];
    #pragma unroll
    for (int i = 0; i < 16; i++) u[i] = up[i];
    const float* er = eh + (size_t)e * 128;
    float p = 0.f;
    for (int ci = 0; ci < 16; ci++){
        int cc = half * 16 + ci;
        int j = cc * 32 + o;
        const float* wr = W2 + (size_t)j * 128;
        float we = b2[j];
        #pragma unroll 8
        for (int hh = 0; hh < 128; hh++) we += er[hh] * wr[hh];
        p += u[ci] * we;
    }
    p += __shfl_xor(p, 1);
    if (half == 0) atomicAdd(&aggr[(size_t)d * 32 + o], p);
}

// ---------------- m = relu(aggr/denom + h @ root_W + conv_b) ----------------
__global__ __launch_bounds__(256) void k_m(const float* __restrict__ aggr,
    const float* __restrict__ deg, const float* __restrict__ h,
    const float* __restrict__ rootW, const float* __restrict__ cb, float* __restrict__ m){
    int gid = blockIdx.x * 256 + threadIdx.x;           // NN*32
    int i = gid >> 5, c = gid & 31;
    float a = aggr[gid] / fmaxf(deg[i], 1.f);
    const float* hr = h + (size_t)i * 32;
    float s = cb[c];
    #pragma unroll
    for (int k = 0; k < 32; k++) s += hr[k] * rootW[k * 32 + c];
    m[gid] = fmaxf(a + s, 0.f);
}

// ---------------- GRU gates gx, gh ----------------
__global__ __launch_bounds__(256) void k_gates(const float* __restrict__ m, const float* __restrict__ h,
    const float* __restrict__ Wih, const float* __restrict__ Whh,
    const float* __restrict__ bih, const float* __restrict__ bhh,
    float* __restrict__ gxa, float* __restrict__ gha){
    int gid = blockIdx.x * 256 + threadIdx.x;           // NN*96
    int i = gid / 96, j = gid - i * 96;
    const float* mr = m + (size_t)i * 32;
    const float* hr = h + (size_t)i * 32;
    const float* wr = Wih + (size_t)j * 32;
    const float* wh = Whh + (size_t)j * 32;
    float gx = bih[j], gh = bhh[j];
    #pragma unroll
    for (int k = 0; k < 32; k++){ gx += mr[k] * wr[k]; gh += hr[k] * wh[k]; }
    gxa[gid] = gx; gha[gid] = gh;
}

// ---------------- GRU update ----------------
__global__ __launch_bounds__(256) void k_upd(const float* __restrict__ gxa, const float* __restrict__ gha,
    float* __restrict__ h){
    int gid = blockIdx.x * 256 + threadIdx.x;           // NN*32
    int i = gid >> 5, c = gid & 31;
    size_t b = (size_t)i * 96;
    float r = sigf(gxa[b + c] + gha[b + c]);
    float z = sigf(gxa[b + 32 + c] + gha[b + 32 + c]);
    float n = tanhf(gxa[b + 64 + c] + r * gha[b + 64 + c]);
    h[gid] = (1.f - z) * n + z * h[gid];
}

// ---------------- Set2Set LSTM step (block per graph) ----------------
__global__ __launch_bounds__(128) void k_lstm(const float* __restrict__ q_star,
    float* __restrict__ hs, float* __restrict__ cs,
    const float* __restrict__ Wih, const float* __restrict__ Whh,
    const float* __restrict__ bih, const float* __restrict__ bhh){
    __shared__ float gbuf[128];
    int g = blockIdx.x, j = threadIdx.x;
    const float* q = q_star + (size_t)g * 64;
    const float* wr = Wih + (size_t)j * 64;
    float acc = bih[j] + bhh[j];
    #pragma unroll 8
    for (int k = 0; k < 64; k++) acc += q[k] * wr[k];
    const float* hr = hs + (size_t)g * 32;
    const float* wh = Whh + (size_t)j * 32;
    #pragma unroll 8
    for (int k = 0; k < 32; k++) acc += hr[k] * wh[k];
    gbuf[j] = acc;
    __syncthreads();
    if (j < 32){
        float iv = sigf(gbuf[j]);
        float fv = sigf(gbuf[32 + j]);
        float gv = tanhf(gbuf[64 + j]);
        float ov = sigf(gbuf[96 + j]);
        float cn = fv * cs[(size_t)g * 32 + j] + iv * gv;
        cs[(size_t)g * 32 + j] = cn;
        hs[(size_t)g * 32 + j] = ov * tanhf(cn);
    }
}

// ---------------- attention pooling (block=64 per graph) ----------------
__global__ __launch_bounds__(64) void k_attn(const float* __restrict__ h, const float* __restrict__ hs,
    const int* __restrict__ starts, float* __restrict__ e_buf, float* __restrict__ q_star){
    int g = blockIdx.x, l = threadIdx.x;
    int s0 = starts[g], s1 = starts[g + 1];
    int c = l & 31, grp = l >> 5;
    float hsv = hs[(size_t)g * 32 + c];
    float mx = -3.4e38f;
    for (int i = s0 + grp; i < s1; i += 2){
        float p = h[(size_t)i * 32 + c] * hsv;
        #pragma unroll
        for (int off = 1; off < 32; off <<= 1) p += __shfl_xor(p, off);
        if (c == 0) e_buf[i] = p;
        mx = fmaxf(mx, p);
    }
    mx = fmaxf(mx, __shfl_xor(mx, 32));
    float ssum = 0.f;
    for (int i = s0 + grp; i < s1; i += 2){
        if (c == 0) ssum += expf(e_buf[i] - mx);
    }
    #pragma unroll
    for (int off = 1; off < 64; off <<= 1) ssum += __shfl_xor(ssum, off);
    float inv = (ssum > 0.f) ? 1.f / ssum : 0.f;
    float acc = 0.f;
    for (int i = s0 + grp; i < s1; i += 2){
        float a = expf(e_buf[i] - mx) * inv;
        acc += a * h[(size_t)i * 32 + c];
    }
    acc += __shfl_xor(acc, 32);
    if (l < 32){
        q_star[(size_t)g * 64 + 32 + c] = acc;
        q_star[(size_t)g * 64 + c] = hsv;
    }
}

// ---------------- final: out = relu(q_star@lin1^T+b1) @ lin2^T + b2 ----------------
__global__ __launch_bounds__(64) void k_final(const float* __restrict__ q_star,
    const float* __restrict__ W1, const float* __restrict__ b1,
    const float* __restrict__ W2, const float* __restrict__ b2, float* __restrict__ out){
    int g = blockIdx.x, l = threadIdx.x;
    float p = 0.f;
    if (l < 32){
        const float* q = q_star + (size_t)g * 64;
        const float* wr = W1 + (size_t)l * 64;
        float s = b1[l];
        #pragma unroll 8
        for (int k = 0; k < 64; k++) s += q[k] * wr[k];
        p = fmaxf(s, 0.f) * W2[l];
    }
    #pragma unroll
    for (int off = 1; off < 64; off <<= 1) p += __shfl_xor(p, off);
    if (l == 0) out[g] = p + b2[0];
}

extern "C" void kernel_launch(void* const* d_in, const int* in_sizes, int n_in,
                              void* d_out, int out_size, void* d_ws, size_t ws_size,
                              hipStream_t stream){
    (void)in_sizes; (void)n_in; (void)out_size;
    const float* x        = (const float*)d_in[0];
    const float* ea       = (const float*)d_in[1];
    const int*   ei       = (const int*)d_in[2];
    const int*   batch    = (const int*)d_in[3];
    const float* lin0_W   = (const float*)d_in[4];
    const float* lin0_b   = (const float*)d_in[5];
    const float* mlp_W1   = (const float*)d_in[6];
    const float* mlp_b1   = (const float*)d_in[7];
    const float* mlp_W2   = (const float*)d_in[8];
    const float* mlp_b2   = (const float*)d_in[9];
    const float* root_W   = (const float*)d_in[10];
    const float* conv_b   = (const float*)d_in[11];
    const float* gWih     = (const float*)d_in[12];
    const float* gWhh     = (const float*)d_in[13];
    const float* gbih     = (const float*)d_in[14];
    const float* gbhh     = (const float*)d_in[15];
    const float* lWih     = (const float*)d_in[16];
    const float* lWhh     = (const float*)d_in[17];
    const float* lbih     = (const float*)d_in[18];
    const float* lbhh     = (const float*)d_in[19];
    const float* lin1_W   = (const float*)d_in[20];
    const float* lin1_b   = (const float*)d_in[21];
    const float* lin2_W   = (const float*)d_in[22];
    const float* lin2_b   = (const float*)d_in[23];
    const int* src = ei;
    const int* dst = ei + NE;
    float* out = (float*)d_out;

    char* w = (char*)d_ws;
    size_t off = 0;
    auto alloc = [&](size_t bytes) -> void* {
        void* p = w + off;
        off = (off + bytes + 255) & ~(size_t)255;
        return p;
    };
    float* h      = (float*)alloc((size_t)NN * 32 * 4);
    float* mbuf   = (float*)alloc((size_t)NN * 32 * 4);
    float* aggr   = (float*)alloc((size_t)NN * 32 * 4);
    float* gxa    = (float*)alloc((size_t)NN * 96 * 4);
    float* gha    = (float*)alloc((size_t)NN * 96 * 4);
    float* deg    = (float*)alloc((size_t)NN * 4);
    float* ehf    = (float*)alloc((size_t)NE * 128 * 4);
    float* e_buf  = (float*)alloc((size_t)NN * 4);
    int*   counts = (int*)alloc((size_t)NB * 4);
    int*   starts = (int*)alloc((size_t)(NB + 1) * 4);
    float* q_star = (float*)alloc((size_t)NB * 64 * 4);
    float* hs     = (float*)alloc((size_t)NB * 32 * 4);
    float* cs     = (float*)alloc((size_t)NB * 32 * 4);
    size_t need_base = off;
    ushortT* WeT = (ushortT*)(w + off);
    size_t need_full = off + (size_t)NE * 1024 * 2;
    bool fast = (ws_size >= need_full);
    if (ws_size < need_base) return;   // cannot run at all

    // zero-init state buffers (poisoned workspace)
    hipMemsetAsync(deg, 0, (size_t)NN * 4, stream);
    hipMemsetAsync(counts, 0, (size_t)NB * 4, stream);
    hipMemsetAsync(q_star, 0, (size_t)NB * 64 * 4, stream);
    hipMemsetAsync(hs, 0, (size_t)NB * 32 * 4, stream);
    hipMemsetAsync(cs, 0, (size_t)NB * 32 * 4, stream);

    k_lin0<<<(NN * 32) / 256, 256, 0, stream>>>(x, lin0_W, lin0_b, h);
    k_edge_mlp<<<(NE * 128) / 256, 256, 0, stream>>>(ea, mlp_W1, mlp_b1, ehf);
    if (fast){
        dim3 grid((NE + 63) / 64, 32);
        k_we_gemm<<<grid, 256, 0, stream>>>(ehf, mlp_W2, mlp_b2, WeT, NE);
    }
    k_deg<<<(NE + 255) / 256, 256, 0, stream>>>(dst, deg, NE);
    k_counts<<<(NN + 255) / 256, 256, 0, stream>>>(batch, counts, NN);
    k_scan<<<1, 1024, 0, stream>>>(counts, starts);

    for (int t = 0; t < 3; t++){
        hipMemsetAsync(aggr, 0, (size_t)NN * 32 * 4, stream);
        if (fast)
            k_msg<<<(NE * 64) / 256, 256, 0, stream>>>(WeT, h, src, dst, aggr, NE);
        else
            k_msg_slow<<<(NE * 64) / 256, 256, 0, stream>>>(ehf, mlp_W2, mlp_b2, h, src, dst, aggr, NE);
        k_m<<<(NN * 32) / 256, 256, 0, stream>>>(aggr, deg, h, root_W, conv_b, mbuf);
        k_gates<<<(NN * 96) / 256, 256, 0, stream>>>(mbuf, h, gWih, gWhh, gbih, gbhh, gxa, gha);
        k_upd<<<(NN * 32) / 256, 256, 0, stream>>>(gxa, gha, h);
    }

    for (int t = 0; t < 3; t++){
        k_lstm<<<NB, 128, 0, stream>>>(q_star, hs, cs, lWih, lWhh, lbih, lbhh);
        k_attn<<<NB, 64, 0, stream>>>(h, hs, starts, e_buf, q_star);
    }
    k_final<<<NB, 64, 0, stream>>>(q_star, lin1_W, lin1_b, lin2_W, lin2_b, out);
}

// Round 3
// 602.491 us; speedup vs baseline: 35.1498x; 35.1498x over previous
//
#include <hip/hip_runtime.h>
#include <hip/hip_bf16.h>
#include <cstdint>

#define NN 40000
#define NE 100000
#define NEP 100032          // NE padded to multiple of 64
#define NB 1024

typedef _Float16 halfT;
typedef _Float16 half8 __attribute__((ext_vector_type(8)));
typedef float f32x4 __attribute__((ext_vector_type(4)));

static __device__ __forceinline__ float sigf(float x){ return 1.f/(1.f + expf(-x)); }

// ---------------- node embed: h = relu(x @ lin0_W^T + b) ----------------
__global__ __launch_bounds__(256) void k_lin0(const float* __restrict__ x,
    const float* __restrict__ W, const float* __restrict__ b, float* __restrict__ h){
    int gid = blockIdx.x * 256 + threadIdx.x;           // NN*32 threads
    int i = gid >> 5, c = gid & 31;
    const float* xr = x + (size_t)i * 30;
    const float* wr = W + (size_t)c * 30;
    float s = b[c];
    #pragma unroll
    for (int f = 0; f < 30; f++) s += xr[f] * wr[f];
    h[gid] = fmaxf(s, 0.f);
}

// ---------------- edge MLP layer 1: ehh = relu(edge_attr @ W1^T + b1) fp16, zero-pad rows
__global__ __launch_bounds__(256) void k_edge_mlp(const float* __restrict__ ea,
    const float* __restrict__ W1, const float* __restrict__ b1, halfT* __restrict__ eh){
    int gid = blockIdx.x * 256 + threadIdx.x;           // NEP*128 threads
    int e = gid >> 7, hh = gid & 127;
    if (e >= NE){ eh[gid] = (halfT)0.f; return; }
    const float* xr = ea + (size_t)e * 11;
    const float* wr = W1 + (size_t)hh * 11;
    float s = b1[hh];
    #pragma unroll
    for (int f = 0; f < 11; f++) s += xr[f] * wr[f];
    eh[gid] = (halfT)fmaxf(s, 0.f);
}

// ---------------- B-matrix prep: Bb2[p][k] = W2[j(p)][k] fp16, j(p)=(p&31)*32 + p/32
__global__ __launch_bounds__(256) void k_prepB(const float* __restrict__ W2, halfT* __restrict__ Bb2){
    int gid = blockIdx.x * 256 + threadIdx.x;           // 1024*128 threads
    int p = gid >> 7, k = gid & 127;
    int j = ((p & 31) << 5) | (p >> 5);
    Bb2[gid] = (halfT)W2[(size_t)j * 128 + k];
}

// ---------------- W_e MFMA GEMM: WeT[e][p] = ehh[e]·Bb2[p] + b2[j(p)], fp16 out
// block: 64 edges x 256 p, 4 waves (wave w owns p-window w*64)
__global__ __launch_bounds__(256) void k_we_mfma(const halfT* __restrict__ ehh,
    const halfT* __restrict__ Bb2, const float* __restrict__ b2,
    halfT* __restrict__ WeT, int ce0){
    __shared__ halfT lout[64 * 264];
    int w = threadIdx.x >> 6, l = threadIdx.x & 63;
    int ebl = blockIdx.x * 64;                 // chunk-local base edge
    int eabs = ce0 + ebl;                      // absolute base edge
    int p0 = blockIdx.y * 256;
    int pw = p0 + w * 64;
    const halfT* A0 = ehh + (size_t)(eabs + (l & 15)) * 128 + (l >> 4) * 8;
    const halfT* B0 = Bb2 + (size_t)(pw + (l & 15)) * 128 + (l >> 4) * 8;
    f32x4 acc[4][4];
    #pragma unroll
    for (int g = 0; g < 4; g++)
        #pragma unroll
        for (int pt = 0; pt < 4; pt++) acc[g][pt] = (f32x4){0.f, 0.f, 0.f, 0.f};
    #pragma unroll
    for (int ks = 0; ks < 4; ks++){
        half8 a[4], bb[4];
        #pragma unroll
        for (int g = 0; g < 4; g++) a[g] = *(const half8*)(A0 + (size_t)g * 16 * 128 + ks * 32);
        #pragma unroll
        for (int pt = 0; pt < 4; pt++) bb[pt] = *(const half8*)(B0 + (size_t)pt * 16 * 128 + ks * 32);
        #pragma unroll
        for (int g = 0; g < 4; g++)
            #pragma unroll
            for (int pt = 0; pt < 4; pt++)
                acc[g][pt] = __builtin_amdgcn_mfma_f32_16x16x32_f16(a[g], bb[pt], acc[g][pt], 0, 0, 0);
    }
    // epilogue: bias add, fp16 convert, LDS transpose
    #pragma unroll
    for (int pt = 0; pt < 4; pt++){
        int p = pw + pt * 16 + (l & 15);
        float bias = b2[((p & 31) << 5) | (p >> 5)];
        int p_loc = w * 64 + pt * 16 + (l & 15);
        #pragma unroll
        for (int g = 0; g < 4; g++)
            #pragma unroll
            for (int r = 0; r < 4; r++){
                int e_loc = g * 16 + (l >> 4) * 4 + r;
                lout[e_loc * 264 + p_loc] = (halfT)(acc[g][pt][r] + bias);
            }
    }
    __syncthreads();
    int tid = threadIdx.x;
    #pragma unroll
    for (int i = 0; i < 8; i++){
        int e_r = i * 8 + (tid >> 5);
        int p_r = (tid & 31) * 8;
        half8 v = *(const half8*)(lout + e_r * 264 + p_r);
        *(half8*)(WeT + (size_t)(ebl + e_r) * 1024 + p0 + p_r) = v;
    }
}

// ---------------- degree & graph counts ----------------
__global__ __launch_bounds__(256) void k_deg(const int* __restrict__ dst, float* __restrict__ deg, int E){
    int e = blockIdx.x * 256 + threadIdx.x;
    if (e < E) atomicAdd(&deg[dst[e]], 1.f);
}
__global__ __launch_bounds__(256) void k_counts(const int* __restrict__ batch, int* __restrict__ counts, int N){
    int i = blockIdx.x * 256 + threadIdx.x;
    if (i < N) atomicAdd(&counts[batch[i]], 1);
}
__global__ __launch_bounds__(1024) void k_scan(const int* __restrict__ counts, int* __restrict__ starts){
    __shared__ int s[1024];
    int t = threadIdx.x;
    s[t] = counts[t];
    __syncthreads();
    for (int off = 1; off < 1024; off <<= 1){
        int v = (t >= off) ? s[t - off] : 0;
        __syncthreads();
        s[t] += v;
        __syncthreads();
    }
    starts[t] = s[t] - counts[t];
    if (t == 1023) starts[1024] = s[1023];
}

// ---------------- message passing: one wave per edge, fp16 W_e ----------------
__global__ __launch_bounds__(256) void k_msg(const halfT* __restrict__ WeT,
    const float* __restrict__ h, const int* __restrict__ src, const int* __restrict__ dst,
    float* __restrict__ aggr, int e0, int e1){
    int e = e0 + ((blockIdx.x * 256 + threadIdx.x) >> 6);
    if (e >= e1) return;
    int l = threadIdx.x & 63;
    int s = src[e], d = dst[e];
    int o = l >> 1, half = l & 1;
    const half8* wp = (const half8*)(WeT + (size_t)(e - e0) * 1024 + o * 32 + half * 16);
    half8 w0 = wp[0], w1 = wp[1];
    const float* up = h + (size_t)s * 32 + half * 16;
    float4 u0 = *(const float4*)(up);
    float4 u1 = *(const float4*)(up + 4);
    float4 u2 = *(const float4*)(up + 8);
    float4 u3 = *(const float4*)(up + 12);
    float p = 0.f;
    p += u0.x * (float)w0[0] + u0.y * (float)w0[1] + u0.z * (float)w0[2] + u0.w * (float)w0[3];
    p += u1.x * (float)w0[4] + u1.y * (float)w0[5] + u1.z * (float)w0[6] + u1.w * (float)w0[7];
    p += u2.x * (float)w1[0] + u2.y * (float)w1[1] + u2.z * (float)w1[2] + u2.w * (float)w1[3];
    p += u3.x * (float)w1[4] + u3.y * (float)w1[5] + u3.z * (float)w1[6] + u3.w * (float)w1[7];
    p += __shfl_xor(p, 1);
    if (half == 0) atomicAdd(&aggr[(size_t)d * 32 + o], p);
}

// ---------------- fused NNConv-epilogue + GRU: h = GRU(m, h) ----------------
__global__ __launch_bounds__(256) void k_gru(const float* __restrict__ aggr,
    const float* __restrict__ deg, float* __restrict__ h,
    const float* __restrict__ rootW, const float* __restrict__ cb,
    const float* __restrict__ Wih, const float* __restrict__ Whh,
    const float* __restrict__ bih, const float* __restrict__ bhh){
    __shared__ float s_root[1024];
    __shared__ float s_wih[3072];
    __shared__ float s_whh[3072];
    __shared__ float s_bih[96], s_bhh[96], s_cb[32];
    int tid = threadIdx.x;
    for (int idx = tid; idx < 1024; idx += 256) s_root[idx] = rootW[idx];
    for (int idx = tid; idx < 3072; idx += 256){ s_wih[idx] = Wih[idx]; s_whh[idx] = Whh[idx]; }
    if (tid < 96){ s_bih[tid] = bih[tid]; s_bhh[tid] = bhh[tid]; }
    if (tid < 32) s_cb[tid] = cb[tid];
    __syncthreads();
    int i = blockIdx.x * 256 + tid;
    if (i >= NN) return;
    float hq[32], mv[32], hn[32];
    const float* hr = h + (size_t)i * 32;
    #pragma unroll
    for (int k = 0; k < 8; k++) *(float4*)&hq[k * 4] = *(const float4*)(hr + k * 4);
    float invd = 1.f / fmaxf(deg[i], 1.f);
    const float* ar = aggr + (size_t)i * 32;
    #pragma unroll
    for (int c = 0; c < 32; c++){
        float s = ar[c] * invd + s_cb[c];
        #pragma unroll
        for (int k = 0; k < 32; k++) s += hq[k] * s_root[k * 32 + c];
        mv[c] = fmaxf(s, 0.f);
    }
    for (int j = 0; j < 32; j++){
        float gxr = s_bih[j], ghr = s_bhh[j];
        float gxz = s_bih[32 + j], ghz = s_bhh[32 + j];
        float gxn = s_bih[64 + j], ghn = s_bhh[64 + j];
        const float* wr0 = &s_wih[j * 32];
        const float* wr1 = &s_wih[(32 + j) * 32];
        const float* wr2 = &s_wih[(64 + j) * 32];
        const float* wh0 = &s_whh[j * 32];
        const float* wh1 = &s_whh[(32 + j) * 32];
        const float* wh2 = &s_whh[(64 + j) * 32];
        #pragma unroll
        for (int k = 0; k < 32; k++){
            float m = mv[k], hh = hq[k];
            gxr += m * wr0[k]; ghr += hh * wh0[k];
            gxz += m * wr1[k]; ghz += hh * wh1[k];
            gxn += m * wr2[k]; ghn += hh * wh2[k];
        }
        float r = sigf(gxr + ghr);
        float z = sigf(gxz + ghz);
        float n = tanhf(gxn + r * ghn);
        hn[j] = (1.f - z) * n + z * hq[j];
    }
    float* hw = h + (size_t)i * 32;
    #pragma unroll
    for (int k = 0; k < 8; k++) *(float4*)(hw + k * 4) = *(const float4*)&hn[k * 4];
}

// ---------------- Set2Set LSTM step (block per graph) ----------------
__global__ __launch_bounds__(128) void k_lstm(const float* __restrict__ q_star,
    float* __restrict__ hs, float* __restrict__ cs,
    const float* __restrict__ Wih, const float* __restrict__ Whh,
    const float* __restrict__ bih, const float* __restrict__ bhh){
    __shared__ float gbuf[128];
    int g = blockIdx.x, j = threadIdx.x;
    const float* q = q_star + (size_t)g * 64;
    const float* wr = Wih + (size_t)j * 64;
    float acc = bih[j] + bhh[j];
    #pragma unroll 8
    for (int k = 0; k < 64; k++) acc += q[k] * wr[k];
    const float* hr = hs + (size_t)g * 32;
    const float* wh = Whh + (size_t)j * 32;
    #pragma unroll 8
    for (int k = 0; k < 32; k++) acc += hr[k] * wh[k];
    gbuf[j] = acc;
    __syncthreads();
    if (j < 32){
        float iv = sigf(gbuf[j]);
        float fv = sigf(gbuf[32 + j]);
        float gv = tanhf(gbuf[64 + j]);
        float ov = sigf(gbuf[96 + j]);
        float cn = fv * cs[(size_t)g * 32 + j] + iv * gv;
        cs[(size_t)g * 32 + j] = cn;
        hs[(size_t)g * 32 + j] = ov * tanhf(cn);
    }
}

// ---------------- attention pooling (block=64 per graph) ----------------
__global__ __launch_bounds__(64) void k_attn(const float* __restrict__ h, const float* __restrict__ hs,
    const int* __restrict__ starts, float* __restrict__ e_buf, float* __restrict__ q_star){
    int g = blockIdx.x, l = threadIdx.x;
    int s0 = starts[g], s1 = starts[g + 1];
    int c = l & 31, grp = l >> 5;
    float hsv = hs[(size_t)g * 32 + c];
    float mx = -3.4e38f;
    for (int i = s0 + grp; i < s1; i += 2){
        float p = h[(size_t)i * 32 + c] * hsv;
        #pragma unroll
        for (int off = 1; off < 32; off <<= 1) p += __shfl_xor(p, off);
        if (c == 0) e_buf[i] = p;
        mx = fmaxf(mx, p);
    }
    mx = fmaxf(mx, __shfl_xor(mx, 32));
    float ssum = 0.f;
    for (int i = s0 + grp; i < s1; i += 2){
        if (c == 0) ssum += expf(e_buf[i] - mx);
    }
    #pragma unroll
    for (int off = 1; off < 64; off <<= 1) ssum += __shfl_xor(ssum, off);
    float inv = (ssum > 0.f) ? 1.f / ssum : 0.f;
    float acc = 0.f;
    for (int i = s0 + grp; i < s1; i += 2){
        float a = expf(e_buf[i] - mx) * inv;
        acc += a * h[(size_t)i * 32 + c];
    }
    acc += __shfl_xor(acc, 32);
    if (l < 32){
        q_star[(size_t)g * 64 + 32 + c] = acc;
        q_star[(size_t)g * 64 + c] = hsv;
    }
}

// ---------------- final: out = relu(q_star@lin1^T+b1) @ lin2^T + b2 ----------------
__global__ __launch_bounds__(64) void k_final(const float* __restrict__ q_star,
    const float* __restrict__ W1, const float* __restrict__ b1,
    const float* __restrict__ W2, const float* __restrict__ b2, float* __restrict__ out){
    int g = blockIdx.x, l = threadIdx.x;
    float p = 0.f;
    if (l < 32){
        const float* q = q_star + (size_t)g * 64;
        const float* wr = W1 + (size_t)l * 64;
        float s = b1[l];
        #pragma unroll 8
        for (int k = 0; k < 64; k++) s += q[k] * wr[k];
        p = fmaxf(s, 0.f) * W2[l];
    }
    #pragma unroll
    for (int off = 1; off < 64; off <<= 1) p += __shfl_xor(p, off);
    if (l == 0) out[g] = p + b2[0];
}

extern "C" void kernel_launch(void* const* d_in, const int* in_sizes, int n_in,
                              void* d_out, int out_size, void* d_ws, size_t ws_size,
                              hipStream_t stream){
    (void)in_sizes; (void)n_in; (void)out_size;
    const float* x        = (const float*)d_in[0];
    const float* ea       = (const float*)d_in[1];
    const int*   ei       = (const int*)d_in[2];
    const int*   batch    = (const int*)d_in[3];
    const float* lin0_W   = (const float*)d_in[4];
    const float* lin0_b   = (const float*)d_in[5];
    const float* mlp_W1   = (const float*)d_in[6];
    const float* mlp_b1   = (const float*)d_in[7];
    const float* mlp_W2   = (const float*)d_in[8];
    const float* mlp_b2   = (const float*)d_in[9];
    const float* root_W   = (const float*)d_in[10];
    const float* conv_b   = (const float*)d_in[11];
    const float* gWih     = (const float*)d_in[12];
    const float* gWhh     = (const float*)d_in[13];
    const float* gbih     = (const float*)d_in[14];
    const float* gbhh     = (const float*)d_in[15];
    const float* lWih     = (const float*)d_in[16];
    const float* lWhh     = (const float*)d_in[17];
    const float* lbih     = (const float*)d_in[18];
    const float* lbhh     = (const float*)d_in[19];
    const float* lin1_W   = (const float*)d_in[20];
    const float* lin1_b   = (const float*)d_in[21];
    const float* lin2_W   = (const float*)d_in[22];
    const float* lin2_b   = (const float*)d_in[23];
    const int* src = ei;
    const int* dst = ei + NE;
    float* out = (float*)d_out;

    char* w = (char*)d_ws;
    size_t off = 0;
    auto alloc = [&](size_t bytes) -> void* {
        void* p = w + off;
        off = (off + bytes + 255) & ~(size_t)255;
        return p;
    };
    float* h      = (float*)alloc((size_t)NN * 32 * 4);
    float* aggr   = (float*)alloc((size_t)NN * 32 * 4);
    float* deg    = (float*)alloc((size_t)NN * 4);
    float* e_buf  = (float*)alloc((size_t)NN * 4);
    int*   counts = (int*)alloc((size_t)NB * 4);
    int*   starts = (int*)alloc((size_t)(NB + 1) * 4);
    float* q_star = (float*)alloc((size_t)NB * 64 * 4);
    float* hs     = (float*)alloc((size_t)NB * 32 * 4);
    float* cs     = (float*)alloc((size_t)NB * 32 * 4);
    halfT* ehh    = (halfT*)alloc((size_t)NEP * 128 * 2);
    halfT* Bb2    = (halfT*)alloc((size_t)1024 * 128 * 2);
    if (ws_size < off + (size_t)64 * 2048) return;     // cannot even hold one chunk
    size_t cap_rows = (ws_size - off) / 2048;          // fp16 W_e rows that fit
    int Ec = (int)((cap_rows > (size_t)NEP) ? NEP : cap_rows);
    Ec &= ~63;
    bool single = (Ec >= NEP);
    halfT* WeT = (halfT*)(w + off);

    hipMemsetAsync(deg, 0, (size_t)NN * 4, stream);
    hipMemsetAsync(counts, 0, (size_t)NB * 4, stream);
    hipMemsetAsync(q_star, 0, (size_t)NB * 64 * 4, stream);
    hipMemsetAsync(hs, 0, (size_t)NB * 32 * 4, stream);
    hipMemsetAsync(cs, 0, (size_t)NB * 32 * 4, stream);

    k_lin0<<<(NN * 32) / 256, 256, 0, stream>>>(x, lin0_W, lin0_b, h);
    k_edge_mlp<<<(NEP * 128) / 256, 256, 0, stream>>>(ea, mlp_W1, mlp_b1, ehh);
    k_prepB<<<(1024 * 128) / 256, 256, 0, stream>>>(mlp_W2, Bb2);
    k_deg<<<(NE + 255) / 256, 256, 0, stream>>>(dst, deg, NE);
    k_counts<<<(NN + 255) / 256, 256, 0, stream>>>(batch, counts, NN);
    k_scan<<<1, 1024, 0, stream>>>(counts, starts);

    if (single){
        dim3 g(NEP / 64, 4);
        k_we_mfma<<<g, 256, 0, stream>>>(ehh, Bb2, mlp_b2, WeT, 0);
    }

    for (int t = 0; t < 3; t++){
        hipMemsetAsync(aggr, 0, (size_t)NN * 32 * 4, stream);
        if (single){
            int nw = NE;
            k_msg<<<(nw + 3) / 4, 256, 0, stream>>>(WeT, h, src, dst, aggr, 0, NE);
        } else {
            for (int c0 = 0; c0 < NEP; c0 += Ec){
                int rows = (NEP - c0 < Ec) ? (NEP - c0) : Ec;
                dim3 g(rows / 64, 4);
                k_we_mfma<<<g, 256, 0, stream>>>(ehh, Bb2, mlp_b2, WeT, c0);
                int e1 = c0 + rows; if (e1 > NE) e1 = NE;
                if (e1 > c0){
                    int nw = e1 - c0;
                    k_msg<<<(nw + 3) / 4, 256, 0, stream>>>(WeT, h, src, dst, aggr, c0, e1);
                }
            }
        }
        k_gru<<<(NN + 255) / 256, 256, 0, stream>>>(aggr, deg, h, root_W, conv_b,
                                                    gWih, gWhh, gbih, gbhh);
    }

    for (int t = 0; t < 3; t++){
        k_lstm<<<NB, 128, 0, stream>>>(q_star, hs, cs, lWih, lWhh, lbih, lbhh);
        k_attn<<<NB, 64, 0, stream>>>(h, hs, starts, e_buf, q_star);
    }
    k_final<<<NB, 64, 0, stream>>>(q_star, lin1_W, lin1_b, lin2_W, lin2_b, out);
}